// Round 10
// baseline (655.739 us; speedup 1.0000x reference)
//
#include <hip/hip_runtime.h>
#include <hip/hip_bf16.h>
#include <cmath>

typedef __hip_bfloat16 bf16;
typedef __attribute__((ext_vector_type(8))) short short8;
typedef __attribute__((ext_vector_type(4))) short short4g;
typedef __attribute__((ext_vector_type(4))) float f32x4;

#define B_     2
#define N_     2048
#define M_     2048
#define D_     1024
#define H_     8
#define DH_    64
#define INNER_ 512
#define FFD_   4096
#define ROWS   4096

__device__ __forceinline__ float b2f(bf16 x){ return __bfloat162float(x); }
__device__ __forceinline__ bf16  f2b(float x){ return __float2bfloat16(x); }
__device__ __forceinline__ float s2f(short s){
    unsigned u = ((unsigned)(unsigned short)s) << 16;
    float f; __builtin_memcpy(&f, &u, 4); return f;
}
__device__ __forceinline__ short f2s(float f){
    bf16 b = __float2bfloat16(f);
    short s; __builtin_memcpy(&s, &b, 2); return s;
}
__device__ __forceinline__ float ldx(const void* p, size_t i, bool isb){
    return isb ? __bfloat162float(((const bf16*)p)[i]) : ((const float*)p)[i];
}
__device__ __forceinline__ void stx(void* p, size_t i, float v, bool isb){
    if (isb) ((bf16*)p)[i] = f2b(v); else ((float*)p)[i] = v;
}
__device__ __forceinline__ void gld16(const bf16* g, bf16* l){
    __builtin_amdgcn_global_load_lds(
        (const __attribute__((address_space(1))) void*)g,
        (__attribute__((address_space(3))) void*)l, 16, 0, 0);
}
// Inline-asm LDS read: opaque to the compiler's mem-dep model so it cannot
// insert an s_waitcnt vmcnt(0) between global_load_lds and the read.
// Caller must do lgkmcnt(0) + sched_barrier(0) before consuming (rule #18).
__device__ __forceinline__ short8 ds_read128(const bf16* p){
    unsigned a = (unsigned)(size_t)(const __attribute__((address_space(3))) bf16*)p;
    short8 r;
    asm volatile("ds_read_b128 %0, %1" : "=v"(r) : "v"(a));
    return r;
}

// ---- dtype probe: ln_x_g is ones. fp32 -> 0x3F800000; bf16 pair -> 0x3F803F80
__global__ void probe_kernel(const void* ones, int* flag){
    unsigned w = *(const unsigned*)ones;
    *flag = (w == 0x3F803F80u) ? 1 : 0;
}

// ---------------- LayerNorm (verified) ----------------
template<bool IN_EXT>
__global__ __launch_bounds__(256) void ln_kernel(const void* __restrict__ x,
    const void* __restrict__ g, const void* __restrict__ b,
    bf16* __restrict__ out, const int* __restrict__ flagp)
{
    const int C = 1024;
    bool f = (*flagp != 0);
    bool bx = IN_EXT ? f : true;
    size_t base = (size_t)blockIdx.x * C;
    int t = threadIdx.x;
    float v[4]; float s = 0.f;
#pragma unroll
    for (int q = 0; q < 4; q++){ v[q] = ldx(x, base + t + q*256, bx); s += v[q]; }
    __shared__ float red[256];
    red[t] = s; __syncthreads();
    for (int o = 128; o > 0; o >>= 1){ if (t < o) red[t] += red[t+o]; __syncthreads(); }
    float mu = red[0] * (1.0f/1024.0f);
    __syncthreads();
    s = 0.f;
#pragma unroll
    for (int q = 0; q < 4; q++){ float d = v[q]-mu; s += d*d; }
    red[t] = s; __syncthreads();
    for (int o = 128; o > 0; o >>= 1){ if (t < o) red[t] += red[t+o]; __syncthreads(); }
    float rstd = rsqrtf(red[0]*(1.0f/1024.0f) + 1e-5f);
    bf16* orow = out + base;
#pragma unroll
    for (int q = 0; q < 4; q++){
        int i = t + q*256;
        orow[i] = f2b((v[q]-mu)*rstd*ldx(g,i,f) + ldx(b,i,f));
    }
}

// ---------------- transpose+cast: out[c][r] = in[r][c] (fp32|bf16 -> bf16) ---
__global__ __launch_bounds__(256) void tcast_kernel(
    const void* __restrict__ in, bf16* __restrict__ out,
    int R, int Ccols, size_t ibs, size_t obs, int force_b16,
    const int* __restrict__ flagp)
{
    bool isb = force_b16 ? true : (*flagp != 0);
    __shared__ float T[32][33];
    size_t ib = (size_t)blockIdx.z * ibs, ob = (size_t)blockIdx.z * obs;
    int r0 = blockIdx.x * 32, c0 = blockIdx.y * 32;
    int tx = threadIdx.x & 31, ty = threadIdx.x >> 5;
#pragma unroll
    for (int rr = 0; rr < 32; rr += 8)
        T[ty + rr][tx] = ldx(in, ib + (size_t)(r0 + ty + rr) * Ccols + c0 + tx, isb);
    __syncthreads();
#pragma unroll
    for (int rr = 0; rr < 32; rr += 8)
        out[ob + (size_t)(c0 + ty + rr) * R + r0 + tx] = f2b(T[tx][ty + rr]);
}

// ---------------- MFMA GEMM, DP-deep pipelined (T3+T4) ---------------------
template<int MODE, int EPI, int DP>
__global__ __launch_bounds__(256) void mfma_gemm(
    const bf16* __restrict__ A, const bf16* __restrict__ A2,
    const bf16* __restrict__ Bt,
    const void* __restrict__ bias, const void* __restrict__ bias2,
    const void* __restrict__ res,  const void* __restrict__ res2,
    void* __restrict__ C, void* __restrict__ C2,
    int K, int lda, int ldb, int ldc,
    size_t coff, size_t cstr, size_t roff, float scale, int bh0,
    int azdiv, size_t astr, size_t bstr, int zsplit,
    const int* __restrict__ flagp)
{
    __shared__ __align__(16) bf16 As[DP][128*32];
    __shared__ __align__(16) bf16 Bs[DP][128*32];
    const int t = threadIdx.x;
    const int wave = t >> 6, lane = t & 63;
    const int quad = lane >> 4, l16 = lane & 15;
    const int z = blockIdx.z;

    const bf16* Ab; const bf16* Bb;
    const void* biasp = bias; const void* resp = res; void* Cp = C;
    size_t cbase;
    if (MODE == 1){
        int bh = bh0 + z, b = bh >> 3, h = bh & 7;
        Ab = A + (size_t)b * N_ * lda + h * DH_ + (size_t)blockIdx.y * 128 * lda;
        Bb = Bt + (size_t)b * M_ * ldb + h * DH_ + (size_t)blockIdx.x * 128 * ldb;
        cbase = coff + (size_t)z * N_ * M_;
    } else {
        const bf16* Ause = A;
        if (z >= zsplit){
            if (A2)    Ause  = A2;
            if (bias2) biasp = bias2;
            if (res2)  resp  = res2;
            if (C2)    Cp    = C2;
        }
        Ab = Ause + (size_t)(z / azdiv) * astr + (size_t)blockIdx.y * 128 * lda;
        Bb = Bt + (size_t)z * bstr + (size_t)blockIdx.x * 128 * ldb;
        cbase = coff + (size_t)z * cstr;
    }

    const int c1 = t, c2 = t + 256;
    const int r1 = c1 >> 2, q1 = ((c1 & 3) - (r1 >> 1)) & 3;
    const int r2 = c2 >> 2, q2 = ((c2 & 3) - (r2 >> 1)) & 3;
    const bf16* ga1 = Ab + (size_t)r1 * lda + q1 * 8;
    const bf16* ga2 = Ab + (size_t)r2 * lda + q2 * 8;
    const bf16* gb1 = Bb + (size_t)r1 * ldb + q1 * 8;
    const bf16* gb2 = Bb + (size_t)r2 * ldb + q2 * 8;
    const int la1 = (wave * 64) * 8;
    const int la2 = (256 + wave * 64) * 8;
    const int moff = (wave & 1) * 64, noff = (wave >> 1) * 64;

    auto stage = [&](int d, int k0){
        gld16(ga1 + k0, &As[d][la1]);
        gld16(ga2 + k0, &As[d][la2]);
        gld16(gb1 + k0, &Bs[d][la1]);
        gld16(gb2 + k0, &Bs[d][la2]);
    };

    f32x4 acc[4][4];
#pragma unroll
    for (int mi = 0; mi < 4; mi++)
#pragma unroll
        for (int ni = 0; ni < 4; ni++)
#pragma unroll
            for (int r = 0; r < 4; r++) acc[mi][ni][r] = 0.f;

    const int nt = K >> 5;
    for (int d = 0; d < DP - 1; ++d)
        if (d < nt) stage(d, d * 32);

    for (int tt = 0; tt < nt; ++tt){
        if (tt + DP - 1 < nt) stage((tt + DP - 1) % DP, (tt + DP - 1) * 32);
        int rem = nt - 1 - tt;
        int lv  = rem < DP - 1 ? rem : DP - 1;
        if      (lv >= 3) asm volatile("s_waitcnt vmcnt(12)" ::: "memory");
        else if (lv == 2) asm volatile("s_waitcnt vmcnt(8)"  ::: "memory");
        else if (lv == 1) asm volatile("s_waitcnt vmcnt(4)"  ::: "memory");
        else              asm volatile("s_waitcnt vmcnt(0)"  ::: "memory");
        __builtin_amdgcn_s_barrier();
        const bf16* Al = As[tt % DP];
        const bf16* Bl = Bs[tt % DP];
        short8 af[4], bf8[4];
#pragma unroll
        for (int mi = 0; mi < 4; mi++){
            int rr = moff + mi*16 + l16;
            int qp = (quad + (rr >> 1)) & 3;
            af[mi] = ds_read128(Al + ((size_t)rr*4 + qp)*8);
        }
#pragma unroll
        for (int ni = 0; ni < 4; ni++){
            int rr = noff + ni*16 + l16;
            int qp = (quad + (rr >> 1)) & 3;
            bf8[ni] = ds_read128(Bl + ((size_t)rr*4 + qp)*8);
        }
        asm volatile("s_waitcnt lgkmcnt(0)" ::: "memory");
        __builtin_amdgcn_sched_barrier(0);
        __builtin_amdgcn_s_setprio(1);
#pragma unroll
        for (int mi = 0; mi < 4; mi++)
#pragma unroll
            for (int ni = 0; ni < 4; ni++)
                acc[mi][ni] = __builtin_amdgcn_mfma_f32_16x16x32_bf16(
                    af[mi], bf8[ni], acc[mi][ni], 0, 0, 0);
        __builtin_amdgcn_s_setprio(0);
        __builtin_amdgcn_s_barrier();
    }

    bool f = false;
    if (EPI >= 1) f = (*flagp != 0);
    const int mb = blockIdx.y * 128, nb = blockIdx.x * 128;
#pragma unroll
    for (int ni = 0; ni < 4; ni++){
        int n = nb + noff + ni*16 + l16;
        float bv = (EPI >= 1) ? ldx(biasp, n, f) : 0.0f;
#pragma unroll
        for (int mi = 0; mi < 4; mi++){
#pragma unroll
            for (int r = 0; r < 4; r++){
                int m = mb + moff + mi*16 + quad*4 + r;
                float val = acc[mi][ni][r] * scale + bv;
                if (EPI == 2) val = 0.5f*val*(1.0f + erff(val*0.70710678118f));
                size_t idx = (size_t)m * ldc + n;
                if (EPI == 3) val += ldx(resp, roff + idx, f);
                if (EPI == 4) val += b2f(((const bf16*)resp)[roff + idx]);
                if (EPI == 4) stx(Cp, cbase + idx, val, f);
                else ((bf16*)Cp)[cbase + idx] = f2b(val);
            }
        }
    }
}

// ---------------- Flash cross-attention (both directions) -------------------
// Grid (32 i-blocks x 64 rows, z=32). z<16: dir0 (Q=qk,K=cqk,V=cvT->aout);
// z>=16 swapped. KVBLK=128. Swapped QK^T: S^T = mfma(K_frag, Q_frag) puts a
// full P-row per lane (q = l16) -> softmax reduces are in-register trees +
// 2 shfl_xor, replacing the 32-op crossbar chains that limited round 9.
#define KSTR 72
#define PSTR 136
__global__ __launch_bounds__(256) void flash_attn(
    const bf16* __restrict__ qk, const bf16* __restrict__ cqk,
    const bf16* __restrict__ vT, const bf16* __restrict__ cvT,
    bf16* __restrict__ aout, bf16* __restrict__ acout)
{
    __shared__ __align__(16) bf16 QP[64*PSTR];  // Q tile, then P (wave-private rows)
    __shared__ __align__(16) bf16 Ks[128*KSTR];
    __shared__ __align__(16) bf16 Vs[64*PSTR];
    const int t = threadIdx.x;
    const int wave = t >> 6, lane = t & 63, quad = lane >> 4, l16 = lane & 15;
    const int z = blockIdx.y;
    const int dir = z >> 4, bh = z & 15, b = bh >> 3, h = bh & 7;
    const bf16 *Qg, *Kg, *Vg; bf16* Og;
    if (dir == 0){ Qg = qk;  Kg = cqk; Vg = cvT; Og = aout;  }
    else         { Qg = cqk; Kg = qk;  Vg = vT;  Og = acout; }
    const int i0 = blockIdx.x * 64;
    const bf16* Qb = Qg + ((size_t)b*2048 + i0)*INNER_ + h*DH_;
    const bf16* Kb = Kg + (size_t)b*2048*INNER_ + h*DH_;
    const bf16* Vb = Vg + ((size_t)b*INNER_ + h*DH_)*2048;

    // stage Q (scaled 0.125 — exact exponent shift in bf16)
    for (int c = t; c < 64*8; c += 256){
        int r = c >> 3, jc = c & 7;
        short8 raw = *(const short8*)(Qb + (size_t)r*INNER_ + jc*8);
        short8 s;
#pragma unroll
        for (int q = 0; q < 8; q++) s[q] = f2s(s2f(raw[q]) * 0.125f);
        *(short8*)(QP + r*PSTR + jc*8) = s;
    }
    __syncthreads();
    const int moff = wave * 16;
    short8 qf[2];
#pragma unroll
    for (int ks = 0; ks < 2; ks++)
        qf[ks] = *(const short8*)(QP + (moff + l16)*PSTR + ks*32 + quad*8);

    f32x4 O[4];
    float mrow = -1e30f, lrow = 0.f;
#pragma unroll
    for (int nd = 0; nd < 4; nd++)
#pragma unroll
        for (int r = 0; r < 4; r++) O[nd][r] = 0.f;

    for (int j0 = 0; j0 < 2048; j0 += 128){
        __syncthreads();                    // WAR: prev-iter Ks/Vs reads done
        // stage K (128 rows x 64 d) and V (64 d x 128 k)
        for (int c = t; c < 128*8; c += 256){
            int r = c >> 3, jc = c & 7;
            short8 kraw = *(const short8*)(Kb + (size_t)(j0 + r)*INNER_ + jc*8);
            *(short8*)(Ks + r*KSTR + jc*8) = kraw;
        }
        for (int c = t; c < 64*16; c += 256){
            int r = c >> 4, jc = c & 15;
            short8 vraw = *(const short8*)(Vb + (size_t)r*2048 + j0 + jc*8);
            *(short8*)(Vs + r*PSTR + jc*8) = vraw;
        }
        __syncthreads();
        // S^T = K Q^T : lane holds q=l16 (fixed), k = ni*16 + quad*4 + r
        f32x4 S[8];
#pragma unroll
        for (int ni = 0; ni < 8; ni++)
#pragma unroll
            for (int r = 0; r < 4; r++) S[ni][r] = 0.f;
#pragma unroll
        for (int ks = 0; ks < 2; ks++){
#pragma unroll
            for (int ni = 0; ni < 8; ni++){
                short8 kf = *(const short8*)(Ks + (ni*16 + l16)*KSTR + ks*32 + quad*8);
                S[ni] = __builtin_amdgcn_mfma_f32_16x16x32_bf16(
                    kf, qf[ks], S[ni], 0, 0, 0);
            }
        }
        // per-lane row softmax (q = l16): in-reg tree + 2 shfl
        float rm = -1e30f;
#pragma unroll
        for (int ni = 0; ni < 8; ni++){
            float a = fmaxf(S[ni][0], S[ni][1]);
            float c2 = fmaxf(S[ni][2], S[ni][3]);
            rm = fmaxf(rm, fmaxf(a, c2));
        }
        rm = fmaxf(rm, __shfl_xor(rm, 16, 64));
        rm = fmaxf(rm, __shfl_xor(rm, 32, 64));
        float mn = fmaxf(mrow, rm);
        float al = __expf(mrow - mn);
        mrow = mn;
        float rs = 0.f;
#pragma unroll
        for (int ni = 0; ni < 8; ni++)
#pragma unroll
            for (int r = 0; r < 4; r++){
                float pv = __expf(S[ni][r] - mn);
                S[ni][r] = pv; rs += pv;
            }
        rs += __shfl_xor(rs, 16, 64);
        rs += __shfl_xor(rs, 32, 64);
        lrow = lrow*al + rs;
        // redistribute alpha to O rows (O row = quad*4+r, alpha lives at lane l16=row)
        float alq[4];
#pragma unroll
        for (int r = 0; r < 4; r++) alq[r] = __shfl(al, quad*4 + r, 64);
#pragma unroll
        for (int nd = 0; nd < 4; nd++)
#pragma unroll
            for (int r = 0; r < 4; r++) O[nd][r] *= alq[r];
        // P write: wave-private rows, packed short4 (k-contiguous)
#pragma unroll
        for (int ni = 0; ni < 8; ni++){
            short4g pk;
#pragma unroll
            for (int r = 0; r < 4; r++) pk[r] = f2s(S[ni][r]);
            *(short4g*)(QP + (moff + l16)*PSTR + ni*16 + quad*4) = pk;
        }
        // O += P V  (no barrier: P rows are wave-private; Vs read-only here)
#pragma unroll
        for (int ks2 = 0; ks2 < 4; ks2++){
            short8 pf = *(const short8*)(QP + (moff + l16)*PSTR + ks2*32 + quad*8);
            short8 vf[4];
#pragma unroll
            for (int nd = 0; nd < 4; nd++)
                vf[nd] = *(const short8*)(Vs + (nd*16 + l16)*PSTR + ks2*32 + quad*8);
#pragma unroll
            for (int nd = 0; nd < 4; nd++)
                O[nd] = __builtin_amdgcn_mfma_f32_16x16x32_bf16(
                    pf, vf[nd], O[nd], 0, 0, 0);
        }
    }
    // epilogue: O / l  (l lives at lane l16=row; O row = quad*4+r)
    float linv[4];
#pragma unroll
    for (int r = 0; r < 4; r++) linv[r] = 1.0f / __shfl(lrow, quad*4 + r, 64);
#pragma unroll
    for (int r = 0; r < 4; r++){
        int row = i0 + moff + quad*4 + r;
#pragma unroll
        for (int nd = 0; nd < 4; nd++){
            int d = nd*16 + l16;
            Og[((size_t)b*2048 + row)*INNER_ + h*DH_ + d] = f2b(O[nd][r] * linv[r]);
        }
    }
}

// --------------------------------------------------------------------------
extern "C" void kernel_launch(void* const* d_in, const int* in_sizes, int n_in,
                              void* d_out, int out_size, void* d_ws, size_t ws_size,
                              hipStream_t stream)
{
    const void* x      = d_in[0];
    const void* ctx    = d_in[1];
    const void* ln_x_g = d_in[4];
    const void* ln_x_b = d_in[5];
    const void* ln_c_g = d_in[6];
    const void* ln_c_b = d_in[7];
    const void* W_qk   = d_in[8];
    const void* W_v    = d_in[9];
    const void* Wc_qk  = d_in[10];
    const void* Wc_v   = d_in[11];
    const void* W_out  = d_in[12];
    const void* b_out  = d_in[13];
    const void* Wc_out = d_in[14];
    const void* bc_out = d_in[15];
    const void* ff_g   = d_in[16];
    const void* ff_b   = d_in[17];
    const void* ff_w1  = d_in[18];
    const void* ff_b1  = d_in[19];
    const void* ff_w2  = d_in[20];
    const void* ff_b2  = d_in[21];
    const void* cff_g  = d_in[22];
    const void* cff_b  = d_in[23];
    const void* cff_w1 = d_in[24];
    const void* cff_b1 = d_in[25];
    const void* cff_w2 = d_in[26];
    const void* cff_b2 = d_in[27];
    (void)in_sizes; (void)n_in; (void)out_size;

    const size_t MB = 1024ull*1024;
    char* p = (char*)d_ws;
    int*  flag = (int*)p;  p += 256;
    bf16* xn   = (bf16*)p; p += 8*MB;
    bf16* cn   = (bf16*)p; p += 8*MB;
    bf16* xmid = (bf16*)p; p += 8*MB;
    bf16* cmid = (bf16*)p; p += 8*MB;
    bf16* Wqk_t  = (bf16*)p; p += 1*MB;
    bf16* Wv_t   = (bf16*)p; p += 1*MB;
    bf16* Wcqk_t = (bf16*)p; p += 1*MB;
    bf16* Wcv_t  = (bf16*)p; p += 1*MB;
    bf16* Wout_t = (bf16*)p; p += 1*MB;
    bf16* Wcout_t= (bf16*)p; p += 1*MB;
    bf16* ffw1_t = (bf16*)p; p += 8*MB;
    bf16* ffw2_t = (bf16*)p; p += 8*MB;
    bf16* cffw1_t= (bf16*)p; p += 8*MB;
    bf16* cffw2_t= (bf16*)p; p += 8*MB;
    char* R = p; p += 32*MB;      // attn bufs; aliased by FFN hidden later
    bf16* qk    = (bf16*)(R +  0*MB);
    bf16* vv    = (bf16*)(R +  4*MB);
    bf16* cqk   = (bf16*)(R +  8*MB);
    bf16* cv    = (bf16*)(R + 12*MB);
    bf16* aout  = (bf16*)(R + 16*MB);
    bf16* acout = (bf16*)(R + 20*MB);
    bf16* vT    = (bf16*)(R + 24*MB);
    bf16* cvT   = (bf16*)(R + 28*MB);
    bf16* hbuf  = (bf16*)R;       // 32MB (x-path FFN hidden; attn bufs dead)
    p = (char*)(((size_t)p + 255) & ~(size_t)255);
    size_t fixed = (size_t)(p - (char*)d_ws);
    bf16* hbuf2 = (bf16*)p;       // 32MB ctx-path FFN hidden
    bool batched_ffn = (ws_size >= fixed + 32*MB);

    // 0. dtype probe
    probe_kernel<<<1, 1, 0, stream>>>(ln_x_g, flag);

    // 1. weight cast+transpose to bf16 [N][K]
    auto TC = [&](const void* in, bf16* o, int Rr, int Cc){
        tcast_kernel<<<dim3(Rr/32, Cc/32, 1), 256, 0, stream>>>(in, o, Rr, Cc, 0, 0, 0, flag);
    };
    TC(W_qk,   Wqk_t,  1024, 512);
    TC(W_v,    Wv_t,   1024, 512);
    TC(Wc_qk,  Wcqk_t, 1024, 512);
    TC(Wc_v,   Wcv_t,  1024, 512);
    TC(W_out,  Wout_t,  512, 1024);
    TC(Wc_out, Wcout_t, 512, 1024);
    TC(ff_w1,  ffw1_t, 1024, 4096);
    TC(ff_w2,  ffw2_t, 4096, 1024);
    TC(cff_w1, cffw1_t,1024, 4096);
    TC(cff_w2, cffw2_t,4096, 1024);

    // 2. pre-norms
    ln_kernel<true><<<ROWS, 256, 0, stream>>>(x,   ln_x_g, ln_x_b, xn, flag);
    ln_kernel<true><<<ROWS, 256, 0, stream>>>(ctx, ln_c_g, ln_c_b, cn, flag);

    // 3. projections — 4-way z-batched (512 blocks)
    mfma_gemm<2,0,4><<<dim3(4,32,4), 256, 0, stream>>>(
        xn, nullptr, Wqk_t, nullptr, nullptr, nullptr, nullptr, qk, nullptr,
        1024, 1024, 1024, 512, 0, (size_t)ROWS*INNER_, 0, 1.f, 0,
        2, (size_t)(cn - xn), (size_t)(Wv_t - Wqk_t), 4, flag);

    // 4. transpose v/cv per batch -> [b][d'][seq]
    tcast_kernel<<<dim3(64,16,2), 256, 0, stream>>>(vv, vT, 2048, 512,
        (size_t)N_*INNER_, (size_t)N_*INNER_, 1, flag);
    tcast_kernel<<<dim3(64,16,2), 256, 0, stream>>>(cv, cvT, 2048, 512,
        (size_t)M_*INNER_, (size_t)M_*INNER_, 1, flag);

    // 5. flash attention, both directions in one dispatch (1024 blocks)
    flash_attn<<<dim3(32, 32), 256, 0, stream>>>(qk, cqk, vT, cvT, aout, acout);

    // 6. output projections + residual — 2-way z-batched (512 blocks)
    mfma_gemm<2,3,4><<<dim3(8,32,2), 256, 0, stream>>>(
        aout, nullptr, Wout_t, b_out, bc_out, x, ctx, xmid, nullptr,
        512, 512, 512, 1024, 0, (size_t)ROWS*D_, 0, 1.f, 0,
        1, (size_t)(acout - aout), (size_t)(Wcout_t - Wout_t), 1, flag);

    // 7+8. dual FFN (batched needs a 2nd 32MB hidden buffer past `fixed`)
    if (batched_ffn){
        ln_kernel<false><<<ROWS, 256, 0, stream>>>(xmid, ff_g,  ff_b,  xn, flag);
        ln_kernel<false><<<ROWS, 256, 0, stream>>>(cmid, cff_g, cff_b, cn, flag);
        mfma_gemm<2,2,2><<<dim3(32,32,2), 256, 0, stream>>>(
            xn, nullptr, ffw1_t, ff_b1, cff_b1, nullptr, nullptr, hbuf, hbuf2,
            1024, 1024, 1024, 4096, 0, 0, 0, 1.f, 0,
            1, (size_t)(cn - xn), (size_t)(cffw1_t - ffw1_t), 1, flag);
        mfma_gemm<2,4,4><<<dim3(8,32,2), 256, 0, stream>>>(
            hbuf, hbuf2, ffw2_t, ff_b2, cff_b2, xmid, cmid, d_out, nullptr,
            4096, 4096, 4096, 1024, 0, (size_t)ROWS*D_, 0, 1.f, 0,
            1, 0, (size_t)(cffw2_t - ffw2_t), 1, flag);
    } else {
        ln_kernel<false><<<ROWS, 256, 0, stream>>>(xmid, ff_g, ff_b, xn, flag);
        mfma_gemm<2,2,2><<<dim3(32,32,1), 256, 0, stream>>>(
            xn, nullptr, ffw1_t, ff_b1, nullptr, nullptr, nullptr, hbuf, nullptr,
            1024, 1024, 1024, 4096, 0, 0, 0, 1.f, 0, 1, 0, 0, 1, flag);
        mfma_gemm<2,4,4><<<dim3(8,32,1), 256, 0, stream>>>(
            hbuf, nullptr, ffw2_t, ff_b2, nullptr, xmid, nullptr, d_out, nullptr,
            4096, 4096, 4096, 1024, 0, 0, 0, 1.f, 0, 1, 0, 0, 1, flag);
        ln_kernel<false><<<ROWS, 256, 0, stream>>>(cmid, cff_g, cff_b, cn, flag);
        mfma_gemm<2,2,2><<<dim3(32,32,1), 256, 0, stream>>>(
            cn, nullptr, cffw1_t, cff_b1, nullptr, nullptr, nullptr, hbuf, nullptr,
            1024, 1024, 1024, 4096, 0, 0, 0, 1.f, 0, 1, 0, 0, 1, flag);
        mfma_gemm<2,4,4><<<dim3(8,32,1), 256, 0, stream>>>(
            hbuf, nullptr, cffw2_t, cff_b2, nullptr, cmid, nullptr, d_out, nullptr,
            4096, 4096, 4096, 1024, (size_t)ROWS*D_, 0, 0, 1.f, 0, 1, 0, 0, 1, flag);
    }
}

// Round 11
// 615.979 us; speedup vs baseline: 1.0645x; 1.0645x over previous
//
#include <hip/hip_runtime.h>
#include <hip/hip_bf16.h>
#include <cmath>

typedef __hip_bfloat16 bf16;
typedef __attribute__((ext_vector_type(8))) short short8;
typedef __attribute__((ext_vector_type(4))) short short4g;
typedef __attribute__((ext_vector_type(4))) float f32x4;

#define B_     2
#define N_     2048
#define M_     2048
#define D_     1024
#define H_     8
#define DH_    64
#define INNER_ 512
#define FFD_   4096
#define ROWS   4096

__device__ __forceinline__ float b2f(bf16 x){ return __bfloat162float(x); }
__device__ __forceinline__ bf16  f2b(float x){ return __float2bfloat16(x); }
__device__ __forceinline__ float s2f(short s){
    unsigned u = ((unsigned)(unsigned short)s) << 16;
    float f; __builtin_memcpy(&f, &u, 4); return f;
}
__device__ __forceinline__ short f2s(float f){
    bf16 b = __float2bfloat16(f);
    short s; __builtin_memcpy(&s, &b, 2); return s;
}
__device__ __forceinline__ float ldx(const void* p, size_t i, bool isb){
    return isb ? __bfloat162float(((const bf16*)p)[i]) : ((const float*)p)[i];
}
__device__ __forceinline__ void stx(void* p, size_t i, float v, bool isb){
    if (isb) ((bf16*)p)[i] = f2b(v); else ((float*)p)[i] = v;
}
__device__ __forceinline__ void gld16(const bf16* g, bf16* l){
    __builtin_amdgcn_global_load_lds(
        (const __attribute__((address_space(1))) void*)g,
        (__attribute__((address_space(3))) void*)l, 16, 0, 0);
}
// Inline-asm LDS read: opaque to the compiler's mem-dep model so it cannot
// insert an s_waitcnt vmcnt(0) between global_load_lds and the read.
// Caller must do lgkmcnt(0) + sched_barrier(0) before consuming (rule #18).
__device__ __forceinline__ short8 ds_read128(const bf16* p){
    unsigned a = (unsigned)(size_t)(const __attribute__((address_space(3))) bf16*)p;
    short8 r;
    asm volatile("ds_read_b128 %0, %1" : "=v"(r) : "v"(a));
    return r;
}

// ---- dtype probe: ln_x_g is ones. fp32 -> 0x3F800000; bf16 pair -> 0x3F803F80
__global__ void probe_kernel(const void* ones, int* flag){
    unsigned w = *(const unsigned*)ones;
    *flag = (w == 0x3F803F80u) ? 1 : 0;
}

// ---------------- LayerNorm (verified) ----------------
template<bool IN_EXT>
__global__ __launch_bounds__(256) void ln_kernel(const void* __restrict__ x,
    const void* __restrict__ g, const void* __restrict__ b,
    bf16* __restrict__ out, const int* __restrict__ flagp)
{
    const int C = 1024;
    bool f = (*flagp != 0);
    bool bx = IN_EXT ? f : true;
    size_t base = (size_t)blockIdx.x * C;
    int t = threadIdx.x;
    float v[4]; float s = 0.f;
#pragma unroll
    for (int q = 0; q < 4; q++){ v[q] = ldx(x, base + t + q*256, bx); s += v[q]; }
    __shared__ float red[256];
    red[t] = s; __syncthreads();
    for (int o = 128; o > 0; o >>= 1){ if (t < o) red[t] += red[t+o]; __syncthreads(); }
    float mu = red[0] * (1.0f/1024.0f);
    __syncthreads();
    s = 0.f;
#pragma unroll
    for (int q = 0; q < 4; q++){ float d = v[q]-mu; s += d*d; }
    red[t] = s; __syncthreads();
    for (int o = 128; o > 0; o >>= 1){ if (t < o) red[t] += red[t+o]; __syncthreads(); }
    float rstd = rsqrtf(red[0]*(1.0f/1024.0f) + 1e-5f);
    bf16* orow = out + base;
#pragma unroll
    for (int q = 0; q < 4; q++){
        int i = t + q*256;
        orow[i] = f2b((v[q]-mu)*rstd*ldx(g,i,f) + ldx(b,i,f));
    }
}

// ---------------- transpose+cast: out[c][r] = in[r][c] (fp32|bf16 -> bf16) ---
__global__ __launch_bounds__(256) void tcast_kernel(
    const void* __restrict__ in, bf16* __restrict__ out,
    int R, int Ccols, size_t ibs, size_t obs, int force_b16,
    const int* __restrict__ flagp)
{
    bool isb = force_b16 ? true : (*flagp != 0);
    __shared__ float T[32][33];
    size_t ib = (size_t)blockIdx.z * ibs, ob = (size_t)blockIdx.z * obs;
    int r0 = blockIdx.x * 32, c0 = blockIdx.y * 32;
    int tx = threadIdx.x & 31, ty = threadIdx.x >> 5;
#pragma unroll
    for (int rr = 0; rr < 32; rr += 8)
        T[ty + rr][tx] = ldx(in, ib + (size_t)(r0 + ty + rr) * Ccols + c0 + tx, isb);
    __syncthreads();
#pragma unroll
    for (int rr = 0; rr < 32; rr += 8)
        out[ob + (size_t)(c0 + ty + rr) * R + r0 + tx] = f2b(T[tx][ty + rr]);
}

// ---------------- MFMA GEMM, DP-deep pipelined (T3+T4) ---------------------
template<int MODE, int EPI, int DP>
__global__ __launch_bounds__(256) void mfma_gemm(
    const bf16* __restrict__ A, const bf16* __restrict__ A2,
    const bf16* __restrict__ Bt,
    const void* __restrict__ bias, const void* __restrict__ bias2,
    const void* __restrict__ res,  const void* __restrict__ res2,
    void* __restrict__ C, void* __restrict__ C2,
    int K, int lda, int ldb, int ldc,
    size_t coff, size_t cstr, size_t roff, float scale, int bh0,
    int azdiv, size_t astr, size_t bstr, int zsplit,
    const int* __restrict__ flagp)
{
    __shared__ __align__(16) bf16 As[DP][128*32];
    __shared__ __align__(16) bf16 Bs[DP][128*32];
    const int t = threadIdx.x;
    const int wave = t >> 6, lane = t & 63;
    const int quad = lane >> 4, l16 = lane & 15;
    const int z = blockIdx.z;

    const bf16* Ab; const bf16* Bb;
    const void* biasp = bias; const void* resp = res; void* Cp = C;
    size_t cbase;
    if (MODE == 1){
        int bh = bh0 + z, b = bh >> 3, h = bh & 7;
        Ab = A + (size_t)b * N_ * lda + h * DH_ + (size_t)blockIdx.y * 128 * lda;
        Bb = Bt + (size_t)b * M_ * ldb + h * DH_ + (size_t)blockIdx.x * 128 * ldb;
        cbase = coff + (size_t)z * N_ * M_;
    } else {
        const bf16* Ause = A;
        if (z >= zsplit){
            if (A2)    Ause  = A2;
            if (bias2) biasp = bias2;
            if (res2)  resp  = res2;
            if (C2)    Cp    = C2;
        }
        Ab = Ause + (size_t)(z / azdiv) * astr + (size_t)blockIdx.y * 128 * lda;
        Bb = Bt + (size_t)z * bstr + (size_t)blockIdx.x * 128 * ldb;
        cbase = coff + (size_t)z * cstr;
    }

    const int c1 = t, c2 = t + 256;
    const int r1 = c1 >> 2, q1 = ((c1 & 3) - (r1 >> 1)) & 3;
    const int r2 = c2 >> 2, q2 = ((c2 & 3) - (r2 >> 1)) & 3;
    const bf16* ga1 = Ab + (size_t)r1 * lda + q1 * 8;
    const bf16* ga2 = Ab + (size_t)r2 * lda + q2 * 8;
    const bf16* gb1 = Bb + (size_t)r1 * ldb + q1 * 8;
    const bf16* gb2 = Bb + (size_t)r2 * ldb + q2 * 8;
    const int la1 = (wave * 64) * 8;
    const int la2 = (256 + wave * 64) * 8;
    const int moff = (wave & 1) * 64, noff = (wave >> 1) * 64;

    auto stage = [&](int d, int k0){
        gld16(ga1 + k0, &As[d][la1]);
        gld16(ga2 + k0, &As[d][la2]);
        gld16(gb1 + k0, &Bs[d][la1]);
        gld16(gb2 + k0, &Bs[d][la2]);
    };

    f32x4 acc[4][4];
#pragma unroll
    for (int mi = 0; mi < 4; mi++)
#pragma unroll
        for (int ni = 0; ni < 4; ni++)
#pragma unroll
            for (int r = 0; r < 4; r++) acc[mi][ni][r] = 0.f;

    const int nt = K >> 5;
    for (int d = 0; d < DP - 1; ++d)
        if (d < nt) stage(d, d * 32);

    for (int tt = 0; tt < nt; ++tt){
        if (tt + DP - 1 < nt) stage((tt + DP - 1) % DP, (tt + DP - 1) * 32);
        int rem = nt - 1 - tt;
        int lv  = rem < DP - 1 ? rem : DP - 1;
        if      (lv >= 3) asm volatile("s_waitcnt vmcnt(12)" ::: "memory");
        else if (lv == 2) asm volatile("s_waitcnt vmcnt(8)"  ::: "memory");
        else if (lv == 1) asm volatile("s_waitcnt vmcnt(4)"  ::: "memory");
        else              asm volatile("s_waitcnt vmcnt(0)"  ::: "memory");
        __builtin_amdgcn_s_barrier();
        const bf16* Al = As[tt % DP];
        const bf16* Bl = Bs[tt % DP];
        short8 af[4], bf8[4];
#pragma unroll
        for (int mi = 0; mi < 4; mi++){
            int rr = moff + mi*16 + l16;
            int qp = (quad + (rr >> 1)) & 3;
            af[mi] = ds_read128(Al + ((size_t)rr*4 + qp)*8);
        }
#pragma unroll
        for (int ni = 0; ni < 4; ni++){
            int rr = noff + ni*16 + l16;
            int qp = (quad + (rr >> 1)) & 3;
            bf8[ni] = ds_read128(Bl + ((size_t)rr*4 + qp)*8);
        }
        asm volatile("s_waitcnt lgkmcnt(0)" ::: "memory");
        __builtin_amdgcn_sched_barrier(0);
        __builtin_amdgcn_s_setprio(1);
#pragma unroll
        for (int mi = 0; mi < 4; mi++)
#pragma unroll
            for (int ni = 0; ni < 4; ni++)
                acc[mi][ni] = __builtin_amdgcn_mfma_f32_16x16x32_bf16(
                    af[mi], bf8[ni], acc[mi][ni], 0, 0, 0);
        __builtin_amdgcn_s_setprio(0);
        __builtin_amdgcn_s_barrier();
    }

    bool f = false;
    if (EPI >= 1) f = (*flagp != 0);
    const int mb = blockIdx.y * 128, nb = blockIdx.x * 128;
#pragma unroll
    for (int ni = 0; ni < 4; ni++){
        int n = nb + noff + ni*16 + l16;
        float bv = (EPI >= 1) ? ldx(biasp, n, f) : 0.0f;
#pragma unroll
        for (int mi = 0; mi < 4; mi++){
#pragma unroll
            for (int r = 0; r < 4; r++){
                int m = mb + moff + mi*16 + quad*4 + r;
                float val = acc[mi][ni][r] * scale + bv;
                if (EPI == 2) val = 0.5f*val*(1.0f + erff(val*0.70710678118f));
                size_t idx = (size_t)m * ldc + n;
                if (EPI == 3) val += ldx(resp, roff + idx, f);
                if (EPI == 4) val += b2f(((const bf16*)resp)[roff + idx]);
                if (EPI == 4) stx(Cp, cbase + idx, val, f);
                else ((bf16*)Cp)[cbase + idx] = f2b(val);
            }
        }
    }
}

// ---------------- Flash cross-attention (both directions) -------------------
// Grid (32 i-blocks x 64 rows, z=32). Swapped QK^T (lane holds q=l16 row).
// T14 async-STAGE: tile t+1's global loads issue right after tile t's
// staging barrier and fly during compute — removes the per-tile exposed
// L2/HBM latency that made rounds 9/10's compute-side changes neutral.
#define KSTR 72
#define PSTR 136
__global__ __launch_bounds__(256) void flash_attn(
    const bf16* __restrict__ qk, const bf16* __restrict__ cqk,
    const bf16* __restrict__ vT, const bf16* __restrict__ cvT,
    bf16* __restrict__ aout, bf16* __restrict__ acout)
{
    __shared__ __align__(16) bf16 QP[64*PSTR];  // Q tile, then P (wave-private rows)
    __shared__ __align__(16) bf16 Ks[128*KSTR];
    __shared__ __align__(16) bf16 Vs[64*PSTR];
    const int t = threadIdx.x;
    const int wave = t >> 6, lane = t & 63, quad = lane >> 4, l16 = lane & 15;
    const int z = blockIdx.y;
    const int dir = z >> 4, bh = z & 15, b = bh >> 3, h = bh & 7;
    const bf16 *Qg, *Kg, *Vg; bf16* Og;
    if (dir == 0){ Qg = qk;  Kg = cqk; Vg = cvT; Og = aout;  }
    else         { Qg = cqk; Kg = qk;  Vg = vT;  Og = acout; }
    const int i0 = blockIdx.x * 64;
    const bf16* Qb = Qg + ((size_t)b*2048 + i0)*INNER_ + h*DH_;
    const bf16* Kb = Kg + (size_t)b*2048*INNER_ + h*DH_;
    const bf16* Vb = Vg + ((size_t)b*INNER_ + h*DH_)*2048;

    // stage Q (scaled 0.125 — exact exponent shift in bf16)
    for (int c = t; c < 64*8; c += 256){
        int r = c >> 3, jc = c & 7;
        short8 raw = *(const short8*)(Qb + (size_t)r*INNER_ + jc*8);
        short8 s;
#pragma unroll
        for (int q = 0; q < 8; q++) s[q] = f2s(s2f(raw[q]) * 0.125f);
        *(short8*)(QP + r*PSTR + jc*8) = s;
    }
    __syncthreads();
    const int moff = wave * 16;
    short8 qf[2];
#pragma unroll
    for (int ks = 0; ks < 2; ks++)
        qf[ks] = *(const short8*)(QP + (moff + l16)*PSTR + ks*32 + quad*8);

    f32x4 O[4];
    float mrow = -1e30f, lrow = 0.f;
#pragma unroll
    for (int nd = 0; nd < 4; nd++)
#pragma unroll
        for (int r = 0; r < 4; r++) O[nd][r] = 0.f;

    // T14 prefetch: per-thread indices (4 K-chunks + 4 V-chunks per tile)
    short8 kreg[4], vreg[4];
#pragma unroll
    for (int i = 0; i < 4; i++){
        int c = t + i*256;
        kreg[i] = *(const short8*)(Kb + (size_t)(c >> 3)*INNER_ + (c & 7)*8);
        vreg[i] = *(const short8*)(Vb + (size_t)(c >> 4)*2048 + (c & 15)*8);
    }

    for (int j0 = 0; j0 < 2048; j0 += 128){
        __syncthreads();                    // WAR: prev-iter Ks/Vs reads done
#pragma unroll
        for (int i = 0; i < 4; i++){
            int c = t + i*256;
            *(short8*)(Ks + (c >> 3)*KSTR + (c & 7)*8) = kreg[i];
            *(short8*)(Vs + (c >> 4)*PSTR + (c & 15)*8) = vreg[i];
        }
        __syncthreads();
        if (j0 + 128 < 2048){               // issue next tile's loads now;
#pragma unroll                              // they fly under this tile's compute
            for (int i = 0; i < 4; i++){
                int c = t + i*256;
                kreg[i] = *(const short8*)(Kb + (size_t)(j0+128 + (c >> 3))*INNER_ + (c & 7)*8);
                vreg[i] = *(const short8*)(Vb + (size_t)(c >> 4)*2048 + j0+128 + (c & 15)*8);
            }
        }
        // S^T = K Q^T : lane holds q=l16 (fixed), k = ni*16 + quad*4 + r
        f32x4 S[8];
#pragma unroll
        for (int ni = 0; ni < 8; ni++)
#pragma unroll
            for (int r = 0; r < 4; r++) S[ni][r] = 0.f;
        __builtin_amdgcn_s_setprio(1);
#pragma unroll
        for (int ks = 0; ks < 2; ks++){
#pragma unroll
            for (int ni = 0; ni < 8; ni++){
                short8 kf = *(const short8*)(Ks + (ni*16 + l16)*KSTR + ks*32 + quad*8);
                S[ni] = __builtin_amdgcn_mfma_f32_16x16x32_bf16(
                    kf, qf[ks], S[ni], 0, 0, 0);
            }
        }
        __builtin_amdgcn_s_setprio(0);
        // per-lane row softmax (q = l16): in-reg tree + 2 shfl
        float rm = -1e30f;
#pragma unroll
        for (int ni = 0; ni < 8; ni++){
            float a = fmaxf(S[ni][0], S[ni][1]);
            float c2 = fmaxf(S[ni][2], S[ni][3]);
            rm = fmaxf(rm, fmaxf(a, c2));
        }
        rm = fmaxf(rm, __shfl_xor(rm, 16, 64));
        rm = fmaxf(rm, __shfl_xor(rm, 32, 64));
        float mn = fmaxf(mrow, rm);
        float al = __expf(mrow - mn);
        mrow = mn;
        float rs = 0.f;
#pragma unroll
        for (int ni = 0; ni < 8; ni++)
#pragma unroll
            for (int r = 0; r < 4; r++){
                float pv = __expf(S[ni][r] - mn);
                S[ni][r] = pv; rs += pv;
            }
        rs += __shfl_xor(rs, 16, 64);
        rs += __shfl_xor(rs, 32, 64);
        lrow = lrow*al + rs;
        // redistribute alpha to O rows (O row = quad*4+r, alpha lives at lane l16=row)
        float alq[4];
#pragma unroll
        for (int r = 0; r < 4; r++) alq[r] = __shfl(al, quad*4 + r, 64);
#pragma unroll
        for (int nd = 0; nd < 4; nd++)
#pragma unroll
            for (int r = 0; r < 4; r++) O[nd][r] *= alq[r];
        // P write: wave-private rows, packed short4 (k-contiguous)
#pragma unroll
        for (int ni = 0; ni < 8; ni++){
            short4g pk;
#pragma unroll
            for (int r = 0; r < 4; r++) pk[r] = f2s(S[ni][r]);
            *(short4g*)(QP + (moff + l16)*PSTR + ni*16 + quad*4) = pk;
        }
        // O += P V  (no barrier: P rows are wave-private; Vs read-only here)
        __builtin_amdgcn_s_setprio(1);
#pragma unroll
        for (int ks2 = 0; ks2 < 4; ks2++){
            short8 pf = *(const short8*)(QP + (moff + l16)*PSTR + ks2*32 + quad*8);
            short8 vf[4];
#pragma unroll
            for (int nd = 0; nd < 4; nd++)
                vf[nd] = *(const short8*)(Vs + (nd*16 + l16)*PSTR + ks2*32 + quad*8);
#pragma unroll
            for (int nd = 0; nd < 4; nd++)
                O[nd] = __builtin_amdgcn_mfma_f32_16x16x32_bf16(
                    pf, vf[nd], O[nd], 0, 0, 0);
        }
        __builtin_amdgcn_s_setprio(0);
    }
    // epilogue: O / l  (l lives at lane l16=row; O row = quad*4+r)
    float linv[4];
#pragma unroll
    for (int r = 0; r < 4; r++) linv[r] = 1.0f / __shfl(lrow, quad*4 + r, 64);
#pragma unroll
    for (int r = 0; r < 4; r++){
        int row = i0 + moff + quad*4 + r;
#pragma unroll
        for (int nd = 0; nd < 4; nd++){
            int d = nd*16 + l16;
            Og[((size_t)b*2048 + row)*INNER_ + h*DH_ + d] = f2b(O[nd][r] * linv[r]);
        }
    }
}

// --------------------------------------------------------------------------
extern "C" void kernel_launch(void* const* d_in, const int* in_sizes, int n_in,
                              void* d_out, int out_size, void* d_ws, size_t ws_size,
                              hipStream_t stream)
{
    const void* x      = d_in[0];
    const void* ctx    = d_in[1];
    const void* ln_x_g = d_in[4];
    const void* ln_x_b = d_in[5];
    const void* ln_c_g = d_in[6];
    const void* ln_c_b = d_in[7];
    const void* W_qk   = d_in[8];
    const void* W_v    = d_in[9];
    const void* Wc_qk  = d_in[10];
    const void* Wc_v   = d_in[11];
    const void* W_out  = d_in[12];
    const void* b_out  = d_in[13];
    const void* Wc_out = d_in[14];
    const void* bc_out = d_in[15];
    const void* ff_g   = d_in[16];
    const void* ff_b   = d_in[17];
    const void* ff_w1  = d_in[18];
    const void* ff_b1  = d_in[19];
    const void* ff_w2  = d_in[20];
    const void* ff_b2  = d_in[21];
    const void* cff_g  = d_in[22];
    const void* cff_b  = d_in[23];
    const void* cff_w1 = d_in[24];
    const void* cff_b1 = d_in[25];
    const void* cff_w2 = d_in[26];
    const void* cff_b2 = d_in[27];
    (void)in_sizes; (void)n_in; (void)out_size;

    const size_t MB = 1024ull*1024;
    char* p = (char*)d_ws;
    int*  flag = (int*)p;  p += 256;
    bf16* xn   = (bf16*)p; p += 8*MB;
    bf16* cn   = (bf16*)p; p += 8*MB;
    bf16* xmid = (bf16*)p; p += 8*MB;
    bf16* cmid = (bf16*)p; p += 8*MB;
    bf16* Wqk_t  = (bf16*)p; p += 1*MB;
    bf16* Wv_t   = (bf16*)p; p += 1*MB;
    bf16* Wcqk_t = (bf16*)p; p += 1*MB;
    bf16* Wcv_t  = (bf16*)p; p += 1*MB;
    bf16* Wout_t = (bf16*)p; p += 1*MB;
    bf16* Wcout_t= (bf16*)p; p += 1*MB;
    bf16* ffw1_t = (bf16*)p; p += 8*MB;
    bf16* ffw2_t = (bf16*)p; p += 8*MB;
    bf16* cffw1_t= (bf16*)p; p += 8*MB;
    bf16* cffw2_t= (bf16*)p; p += 8*MB;
    char* R = p; p += 32*MB;      // attn bufs; aliased by FFN hidden later
    bf16* qk    = (bf16*)(R +  0*MB);
    bf16* vv    = (bf16*)(R +  4*MB);
    bf16* cqk   = (bf16*)(R +  8*MB);
    bf16* cv    = (bf16*)(R + 12*MB);
    bf16* aout  = (bf16*)(R + 16*MB);
    bf16* acout = (bf16*)(R + 20*MB);
    bf16* vT    = (bf16*)(R + 24*MB);
    bf16* cvT   = (bf16*)(R + 28*MB);
    bf16* hbuf  = (bf16*)R;       // 32MB (x-path FFN hidden; attn bufs dead)
    p = (char*)(((size_t)p + 255) & ~(size_t)255);
    size_t fixed = (size_t)(p - (char*)d_ws);
    bf16* hbuf2 = (bf16*)p;       // 32MB ctx-path FFN hidden
    bool batched_ffn = (ws_size >= fixed + 32*MB);

    // 0. dtype probe
    probe_kernel<<<1, 1, 0, stream>>>(ln_x_g, flag);

    // 1. weight cast+transpose to bf16 [N][K]
    auto TC = [&](const void* in, bf16* o, int Rr, int Cc){
        tcast_kernel<<<dim3(Rr/32, Cc/32, 1), 256, 0, stream>>>(in, o, Rr, Cc, 0, 0, 0, flag);
    };
    TC(W_qk,   Wqk_t,  1024, 512);
    TC(W_v,    Wv_t,   1024, 512);
    TC(Wc_qk,  Wcqk_t, 1024, 512);
    TC(Wc_v,   Wcv_t,  1024, 512);
    TC(W_out,  Wout_t,  512, 1024);
    TC(Wc_out, Wcout_t, 512, 1024);
    TC(ff_w1,  ffw1_t, 1024, 4096);
    TC(ff_w2,  ffw2_t, 4096, 1024);
    TC(cff_w1, cffw1_t,1024, 4096);
    TC(cff_w2, cffw2_t,4096, 1024);

    // 2. pre-norms
    ln_kernel<true><<<ROWS, 256, 0, stream>>>(x,   ln_x_g, ln_x_b, xn, flag);
    ln_kernel<true><<<ROWS, 256, 0, stream>>>(ctx, ln_c_g, ln_c_b, cn, flag);

    // 3. projections — 4-way z-batched (512 blocks)
    mfma_gemm<2,0,4><<<dim3(4,32,4), 256, 0, stream>>>(
        xn, nullptr, Wqk_t, nullptr, nullptr, nullptr, nullptr, qk, nullptr,
        1024, 1024, 1024, 512, 0, (size_t)ROWS*INNER_, 0, 1.f, 0,
        2, (size_t)(cn - xn), (size_t)(Wv_t - Wqk_t), 4, flag);

    // 4. transpose v/cv per batch -> [b][d'][seq]
    tcast_kernel<<<dim3(64,16,2), 256, 0, stream>>>(vv, vT, 2048, 512,
        (size_t)N_*INNER_, (size_t)N_*INNER_, 1, flag);
    tcast_kernel<<<dim3(64,16,2), 256, 0, stream>>>(cv, cvT, 2048, 512,
        (size_t)M_*INNER_, (size_t)M_*INNER_, 1, flag);

    // 5. flash attention, both directions in one dispatch (1024 blocks)
    flash_attn<<<dim3(32, 32), 256, 0, stream>>>(qk, cqk, vT, cvT, aout, acout);

    // 6. output projections + residual — 2-way z-batched (512 blocks)
    mfma_gemm<2,3,4><<<dim3(8,32,2), 256, 0, stream>>>(
        aout, nullptr, Wout_t, b_out, bc_out, x, ctx, xmid, nullptr,
        512, 512, 512, 1024, 0, (size_t)ROWS*D_, 0, 1.f, 0,
        1, (size_t)(acout - aout), (size_t)(Wcout_t - Wout_t), 1, flag);

    // 7+8. dual FFN (batched needs a 2nd 32MB hidden buffer past `fixed`)
    if (batched_ffn){
        ln_kernel<false><<<ROWS, 256, 0, stream>>>(xmid, ff_g,  ff_b,  xn, flag);
        ln_kernel<false><<<ROWS, 256, 0, stream>>>(cmid, cff_g, cff_b, cn, flag);
        mfma_gemm<2,2,2><<<dim3(32,32,2), 256, 0, stream>>>(
            xn, nullptr, ffw1_t, ff_b1, cff_b1, nullptr, nullptr, hbuf, hbuf2,
            1024, 1024, 1024, 4096, 0, 0, 0, 1.f, 0,
            1, (size_t)(cn - xn), (size_t)(cffw1_t - ffw1_t), 1, flag);
        mfma_gemm<2,4,4><<<dim3(8,32,2), 256, 0, stream>>>(
            hbuf, hbuf2, ffw2_t, ff_b2, cff_b2, xmid, cmid, d_out, nullptr,
            4096, 4096, 4096, 1024, 0, (size_t)ROWS*D_, 0, 1.f, 0,
            1, 0, (size_t)(cffw2_t - ffw2_t), 1, flag);
    } else {
        ln_kernel<false><<<ROWS, 256, 0, stream>>>(xmid, ff_g, ff_b, xn, flag);
        mfma_gemm<2,2,2><<<dim3(32,32,1), 256, 0, stream>>>(
            xn, nullptr, ffw1_t, ff_b1, nullptr, nullptr, nullptr, hbuf, nullptr,
            1024, 1024, 1024, 4096, 0, 0, 0, 1.f, 0, 1, 0, 0, 1, flag);
        mfma_gemm<2,4,4><<<dim3(8,32,1), 256, 0, stream>>>(
            hbuf, nullptr, ffw2_t, ff_b2, nullptr, xmid, nullptr, d_out, nullptr,
            4096, 4096, 4096, 1024, 0, 0, 0, 1.f, 0, 1, 0, 0, 1, flag);
        ln_kernel<false><<<ROWS, 256, 0, stream>>>(cmid, cff_g, cff_b, cn, flag);
        mfma_gemm<2,2,2><<<dim3(32,32,1), 256, 0, stream>>>(
            cn, nullptr, cffw1_t, cff_b1, nullptr, nullptr, nullptr, hbuf, nullptr,
            1024, 1024, 1024, 4096, 0, 0, 0, 1.f, 0, 1, 0, 0, 1, flag);
        mfma_gemm<2,4,4><<<dim3(8,32,1), 256, 0, stream>>>(
            hbuf, nullptr, cffw2_t, cff_b2, nullptr, cmid, nullptr, d_out, nullptr,
            4096, 4096, 4096, 1024, (size_t)ROWS*D_, 0, 0, 1.f, 0, 1, 0, 0, 1, flag);
    }
}